// Round 5
// baseline (1992.876 us; speedup 1.0000x reference)
//
#include <hip/hip_runtime.h>
#include <math.h>

typedef __attribute__((ext_vector_type(4))) float f32x4;
typedef __attribute__((ext_vector_type(8))) short bf16x8;
typedef __attribute__((ext_vector_type(4))) unsigned short u16x4;

__device__ __forceinline__ unsigned short f2bf(float f) {
  union { float f; unsigned u; } v; v.f = f;
  return (unsigned short)((v.u + 0x7fffu + ((v.u >> 16) & 1u)) >> 16);
}

__device__ __forceinline__ f32x4 zero4() {
  f32x4 z; z[0] = z[1] = z[2] = z[3] = 0.f; return z;
}

__device__ __forceinline__ f32x4 mfma16(bf16x8 a, bf16x8 b, f32x4 c) {
  return __builtin_amdgcn_mfma_f32_16x16x32_bf16(a, b, c, 0, 0, 0);
}

// ---------------------------------------------------------------------------
// K0: convert weights f32 -> bf16 into workspace
// ---------------------------------------------------------------------------
__global__ void cvt_kernel(const float* __restrict__ pw, const float* __restrict__ f1,
                           const float* __restrict__ f2, unsigned short* __restrict__ opw,
                           unsigned short* __restrict__ of1, unsigned short* __restrict__ of2) {
  const long stride = (long)gridDim.x * blockDim.x;
  const long t0 = (long)blockIdx.x * blockDim.x + threadIdx.x;
  for (long i = t0; i < 512L * 512; i += stride) opw[i] = f2bf(pw[i]);
  for (long i = t0; i < 2048L * 512; i += stride) of1[i] = f2bf(f1[i]);
  for (long i = t0; i < 512L * 2048; i += stride) of2[i] = f2bf(f2[i]);
}

// ---------------------------------------------------------------------------
// K1: window attention. grid=1024 windows, 256 thr (4 waves), 4 heads/wave.
// P stored directly as bf16 in padded LDS ([64][72], 36.8 KB total -> 4 blk/CU).
// ---------------------------------------------------------------------------
__global__ __launch_bounds__(256) void attn_kernel(
    const float* __restrict__ q, const float* __restrict__ k,
    const float* __restrict__ v, const float* __restrict__ rpb,
    unsigned short* __restrict__ O) {
  __shared__ __align__(16) unsigned short Plds[4][64][72];  // bf16 P, +8 pad
  const int w = blockIdx.x;
  const int tid = threadIdx.x;
  const int wv = tid >> 6;
  const int lane = tid & 63;
  const int l16 = lane & 15;
  const int g = lane >> 4;
  unsigned short (*P)[72] = Plds[wv];
  const float scale = 0.17677669529663687f;  // 32^-0.5
  const long base = (long)w * (64 * 512);

  for (int hi = 0; hi < 4; ++hi) {
    const int h = wv * 4 + hi;
    bf16x8 aq[4], bk[4];
#pragma unroll
    for (int t = 0; t < 4; ++t) {
      const float* qp = q + base + (long)(t * 16 + l16) * 512 + h * 32 + g * 8;
      const float* kp = k + base + (long)(t * 16 + l16) * 512 + h * 32 + g * 8;
      f32x4 q0 = *(const f32x4*)qp, q1 = *(const f32x4*)(qp + 4);
      f32x4 k0 = *(const f32x4*)kp, k1 = *(const f32x4*)(kp + 4);
#pragma unroll
      for (int j = 0; j < 4; ++j) {
        aq[t][j]     = (short)f2bf(q0[j] * scale);
        aq[t][j + 4] = (short)f2bf(q1[j] * scale);
        bk[t][j]     = (short)f2bf(k0[j]);
        bk[t][j + 4] = (short)f2bf(k1[j]);
      }
    }
    f32x4 acc[4][4];
#pragma unroll
    for (int a = 0; a < 4; ++a)
#pragma unroll
      for (int b = 0; b < 4; ++b) acc[a][b] = zero4();
#pragma unroll
    for (int a = 0; a < 4; ++a)
#pragma unroll
      for (int b = 0; b < 4; ++b) acc[a][b] = mfma16(aq[a], bk[b], acc[a][b]);

    // softmax over 64 cols per row, then + rel-pos bias (AFTER softmax), -> LDS bf16
#pragma unroll
    for (int tm = 0; tm < 4; ++tm) {
      f32x4 mx;
#pragma unroll
      for (int i = 0; i < 4; ++i)
        mx[i] = fmaxf(fmaxf(acc[tm][0][i], acc[tm][1][i]),
                      fmaxf(acc[tm][2][i], acc[tm][3][i]));
#pragma unroll
      for (int off = 1; off < 16; off <<= 1)
#pragma unroll
        for (int i = 0; i < 4; ++i)
          mx[i] = fmaxf(mx[i], __shfl_xor(mx[i], off, 64));
      f32x4 sm = zero4();
#pragma unroll
      for (int tc = 0; tc < 4; ++tc)
#pragma unroll
        for (int i = 0; i < 4; ++i) {
          acc[tm][tc][i] = __expf(acc[tm][tc][i] - mx[i]);
          sm[i] += acc[tm][tc][i];
        }
#pragma unroll
      for (int off = 1; off < 16; off <<= 1)
#pragma unroll
        for (int i = 0; i < 4; ++i) sm[i] += __shfl_xor(sm[i], off, 64);
      f32x4 inv;
#pragma unroll
      for (int i = 0; i < 4; ++i) inv[i] = 1.0f / sm[i];
#pragma unroll
      for (int tc = 0; tc < 4; ++tc)
#pragma unroll
        for (int i = 0; i < 4; ++i) {
          int n = tm * 16 + g * 4 + i;   // query token (row)
          int m = tc * 16 + l16;         // key token (col)
          int idx = ((n >> 3) - (m >> 3) + 7) * 15 + ((n & 7) - (m & 7) + 7);
          P[n][m] = f2bf(acc[tm][tc][i] * inv[i] + rpb[idx * 16 + h]);
        }
    }

    // O = P @ vh   (M=64 x N=32 x K=64 -> 4x2 tiles, 2 k-steps)
    f32x4 oc[4][2];
#pragma unroll
    for (int a = 0; a < 4; ++a) { oc[a][0] = zero4(); oc[a][1] = zero4(); }
#pragma unroll
    for (int ks = 0; ks < 2; ++ks) {
      bf16x8 ap[4];
#pragma unroll
      for (int tm = 0; tm < 4; ++tm)
        ap[tm] = *(const bf16x8*)&P[tm * 16 + l16][ks * 32 + g * 8];
      bf16x8 bv[2];
#pragma unroll
      for (int tn = 0; tn < 2; ++tn)
#pragma unroll
        for (int j = 0; j < 8; ++j) {
          int m = ks * 32 + g * 8 + j;
          bv[tn][j] = (short)f2bf(v[base + (long)m * 512 + h * 32 + tn * 16 + l16]);
        }
#pragma unroll
      for (int tm = 0; tm < 4; ++tm)
#pragma unroll
        for (int tn = 0; tn < 2; ++tn) oc[tm][tn] = mfma16(ap[tm], bv[tn], oc[tm][tn]);
    }
#pragma unroll
    for (int tm = 0; tm < 4; ++tm)
#pragma unroll
      for (int tn = 0; tn < 2; ++tn)
#pragma unroll
        for (int i = 0; i < 4; ++i) {
          int n = tm * 16 + g * 4 + i;
          O[base + (long)n * 512 + h * 32 + tn * 16 + l16] = f2bf(oc[tm][tn][i]);
        }
  }
}

// ---------------------------------------------------------------------------
// K2: proj GEMM (per window 64x512x512) + bias + gamma1*() + x residual,
// scattered (window_reverse) into y == d_out (f32).
// ---------------------------------------------------------------------------
__global__ __launch_bounds__(256) void proj_kernel(
    const unsigned short* __restrict__ O, const unsigned short* __restrict__ pw,
    const float* __restrict__ pb, const float* __restrict__ gamma1,
    const float* __restrict__ x, float* __restrict__ y) {
  const int w = blockIdx.x;
  const int tid = threadIdx.x;
  const int wv = tid >> 6, lane = tid & 63;
  const int l16 = lane & 15, g = lane >> 4;
  const long obase = (long)w * (64 * 512);
  f32x4 acc[4][8];
#pragma unroll
  for (int a = 0; a < 4; ++a)
#pragma unroll
    for (int b = 0; b < 8; ++b) acc[a][b] = zero4();

  for (int kk = 0; kk < 512; kk += 32) {
    bf16x8 a[4];
#pragma unroll
    for (int tm = 0; tm < 4; ++tm)
      a[tm] = *(const bf16x8*)(O + obase + (long)(tm * 16 + l16) * 512 + kk + g * 8);
#pragma unroll
    for (int tn = 0; tn < 8; ++tn) {
      int c = wv * 128 + tn * 16 + l16;
      bf16x8 b = *(const bf16x8*)(pw + (long)c * 512 + kk + g * 8);
#pragma unroll
      for (int tm = 0; tm < 4; ++tm) acc[tm][tn] = mfma16(a[tm], b, acc[tm][tn]);
    }
  }
  const int bi = w >> 6, wh = (w >> 3) & 7, wc = w & 7;
#pragma unroll
  for (int tn = 0; tn < 8; ++tn) {
    int c = wv * 128 + tn * 16 + l16;
    float g1c = gamma1[c], pbc = pb[c];
#pragma unroll
    for (int tm = 0; tm < 4; ++tm)
#pragma unroll
      for (int i = 0; i < 4; ++i) {
        int n = tm * 16 + g * 4 + i;
        long t = (long)(bi * 64 + wh * 8 + (n >> 3)) * 64 + wc * 8 + (n & 7);
        y[t * 512 + c] = x[t * 512 + c] + g1c * (acc[tm][tn][i] + pbc);
      }
  }
}

// ---------------------------------------------------------------------------
// K3: LN2 + fused MLP (512->2048 GELU ->512) + gamma2 residual, in-place on y.
// LDS = yn 64KB (bf16, XOR-swizzled) + h1 16KB = 80KB -> 2 blocks/CU.
// LN stats via 4-lane shuffle (no LDS). XOR swizzle byte^((row&7)<<4) on both
// LDS tiles kills the 1024B/256B row-stride ds_read_b128 bank conflicts.
// ---------------------------------------------------------------------------
__global__ __launch_bounds__(256) void mlp_kernel(
    float* __restrict__ y,
    const unsigned short* __restrict__ f1w, const float* __restrict__ f1b,
    const unsigned short* __restrict__ f2w, const float* __restrict__ f2b,
    const float* __restrict__ lnw, const float* __restrict__ lnb,
    const float* __restrict__ g2) {
  __shared__ __align__(16) unsigned short yn[64 * 512];   // 64 KB
  __shared__ __align__(16) unsigned short h1[64 * 128];   // 16 KB
  const int tid = threadIdx.x;
  const long T0 = (long)blockIdx.x * 64;

  {  // fused LN: 4 threads/row, shuffle-reduced stats, swizzled bf16 store
    const int r = tid >> 2, sg = tid & 3;
    const float* yr = y + (T0 + r) * 512 + sg * 128;
    float s = 0.f, s2 = 0.f;
    for (int j = 0; j < 128; j += 4) {
      f32x4 t = *(const f32x4*)(yr + j);
      s += t[0] + t[1] + t[2] + t[3];
      s2 += t[0] * t[0] + t[1] * t[1] + t[2] * t[2] + t[3] * t[3];
    }
    s += __shfl_xor(s, 1, 64);  s += __shfl_xor(s, 2, 64);
    s2 += __shfl_xor(s2, 1, 64); s2 += __shfl_xor(s2, 2, 64);
    const float mu = s * (1.f / 512.f);
    const float rs = rsqrtf(s2 * (1.f / 512.f) - mu * mu + 1e-5f);
    char* ynb = (char*)yn;
    for (int j = 0; j < 128; j += 4) {
      f32x4 t = *(const f32x4*)(yr + j);
      f32x4 w4 = *(const f32x4*)(lnw + sg * 128 + j);
      f32x4 b4 = *(const f32x4*)(lnb + sg * 128 + j);
      u16x4 o;
#pragma unroll
      for (int e = 0; e < 4; ++e) o[e] = f2bf((t[e] - mu) * rs * w4[e] + b4[e]);
      int byte = (r * 1024 + (sg * 128 + j) * 2) ^ ((r & 7) << 4);
      *(u16x4*)(ynb + byte) = o;
    }
  }
  __syncthreads();

  const int wv = tid >> 6, lane = tid & 63;
  const int l16 = lane & 15, g = lane >> 4;
  const char* ynb = (const char*)yn;
  const char* h1b = (const char*)h1;
  char* h1w = (char*)h1;
  f32x4 acc[4][8];
#pragma unroll
  for (int a = 0; a < 4; ++a)
#pragma unroll
    for (int b = 0; b < 8; ++b) acc[a][b] = zero4();

  for (int ic = 0; ic < 16; ++ic) {
    const int ib = ic * 128;   // inner-dim chunk of 128
    // fc1: this wave computes h1[:, wv*32 .. +32)
    f32x4 acc2[4][2];
#pragma unroll
    for (int a = 0; a < 4; ++a) { acc2[a][0] = zero4(); acc2[a][1] = zero4(); }
    for (int kk = 0; kk < 512; kk += 32) {
      bf16x8 a[4];
#pragma unroll
      for (int tm = 0; tm < 4; ++tm)
        a[tm] = *(const bf16x8*)(ynb + (((tm * 16 + l16) * 1024 + (kk + g * 8) * 2)
                                       ^ ((l16 & 7) << 4)));
#pragma unroll
      for (int tn = 0; tn < 2; ++tn) {
        long irow = ib + wv * 32 + tn * 16 + l16;
        bf16x8 b = *(const bf16x8*)(f1w + irow * 512 + kk + g * 8);
#pragma unroll
        for (int tm = 0; tm < 4; ++tm) acc2[tm][tn] = mfma16(a[tm], b, acc2[tm][tn]);
      }
    }
    __syncthreads();  // prev chunk's h1 fully consumed
#pragma unroll
    for (int tm = 0; tm < 4; ++tm)
#pragma unroll
      for (int tn = 0; tn < 2; ++tn)
#pragma unroll
        for (int i = 0; i < 4; ++i) {
          int row = tm * 16 + g * 4 + i;
          int cl = wv * 32 + tn * 16 + l16;
          float val = acc2[tm][tn][i] + f1b[ib + cl];
          float gg = 0.5f * val * (1.f + erff(val * 0.70710678118654752f));  // exact GELU
          *(unsigned short*)(h1w + ((row * 256 + cl * 2) ^ ((row & 7) << 4))) = f2bf(gg);
        }
    __syncthreads();  // h1 ready
    // fc2: accumulate this wave's 128 output cols over this inner chunk
    for (int kk = 0; kk < 128; kk += 32) {
      bf16x8 a[4];
#pragma unroll
      for (int tm = 0; tm < 4; ++tm)
        a[tm] = *(const bf16x8*)(h1b + (((tm * 16 + l16) * 256 + (kk + g * 8) * 2)
                                       ^ ((l16 & 7) << 4)));
#pragma unroll
      for (int tn = 0; tn < 8; ++tn) {
        int c = wv * 128 + tn * 16 + l16;
        bf16x8 b = *(const bf16x8*)(f2w + (long)c * 2048 + ib + kk + g * 8);
#pragma unroll
        for (int tm = 0; tm < 4; ++tm) acc[tm][tn] = mfma16(a[tm], b, acc[tm][tn]);
      }
    }
  }
#pragma unroll
  for (int tn = 0; tn < 8; ++tn) {
    int c = wv * 128 + tn * 16 + l16;
    float g2c = g2[c], fbc = f2b[c];
#pragma unroll
    for (int tm = 0; tm < 4; ++tm)
#pragma unroll
      for (int i = 0; i < 4; ++i) {
        long t = T0 + tm * 16 + g * 4 + i;
        y[t * 512 + c] += g2c * (acc[tm][tn][i] + fbc);
      }
  }
}

// ---------------------------------------------------------------------------
extern "C" void kernel_launch(void* const* d_in, const int* in_sizes, int n_in,
                              void* d_out, int out_size, void* d_ws, size_t ws_size,
                              hipStream_t stream) {
  const float* x   = (const float*)d_in[0];
  const float* q   = (const float*)d_in[1];
  const float* k   = (const float*)d_in[2];
  const float* v   = (const float*)d_in[3];
  const float* pw  = (const float*)d_in[4];
  const float* pb  = (const float*)d_in[5];
  const float* rpb = (const float*)d_in[6];
  const float* g1  = (const float*)d_in[7];
  const float* lnw = (const float*)d_in[8];
  const float* lnb = (const float*)d_in[9];
  const float* f1w = (const float*)d_in[10];
  const float* f1b = (const float*)d_in[11];
  const float* f2w = (const float*)d_in[12];
  const float* f2b = (const float*)d_in[13];
  const float* g2  = (const float*)d_in[14];
  float* y = (float*)d_out;

  unsigned short* Ob   = (unsigned short*)d_ws;            // 1024*64*512 bf16 = 64 MB
  unsigned short* pwb  = Ob + (size_t)1024 * 64 * 512;     // 512*512
  unsigned short* f1wb = pwb + 512 * 512;                  // 2048*512
  unsigned short* f2wb = f1wb + 2048 * 512;                // 512*2048

  hipLaunchKernelGGL(cvt_kernel, dim3(1024), dim3(256), 0, stream,
                     pw, f1w, f2w, pwb, f1wb, f2wb);
  hipLaunchKernelGGL(attn_kernel, dim3(1024), dim3(256), 0, stream,
                     q, k, v, rpb, Ob);
  hipLaunchKernelGGL(proj_kernel, dim3(1024), dim3(256), 0, stream,
                     Ob, pwb, pb, g1, x, y);
  hipLaunchKernelGGL(mlp_kernel, dim3(1024), dim3(256), 0, stream,
                     y, f1wb, f1b, f2wb, f2b, lnw, lnb, g2);
}

// Round 10
// 1441.765 us; speedup vs baseline: 1.3822x; 1.3822x over previous
//
#include <hip/hip_runtime.h>
#include <math.h>

typedef __attribute__((ext_vector_type(4))) float f32x4;
typedef __attribute__((ext_vector_type(8))) short bf16x8;
typedef __attribute__((ext_vector_type(4))) unsigned short u16x4;
typedef __attribute__((ext_vector_type(8))) unsigned short u16x8;

__device__ __forceinline__ unsigned short f2bf(float f) {
  union { float f; unsigned u; } v; v.f = f;
  return (unsigned short)((v.u + 0x7fffu + ((v.u >> 16) & 1u)) >> 16);
}

__device__ __forceinline__ f32x4 zero4() {
  f32x4 z; z[0] = z[1] = z[2] = z[3] = 0.f; return z;
}

__device__ __forceinline__ f32x4 mfma16(bf16x8 a, bf16x8 b, f32x4 c) {
  return __builtin_amdgcn_mfma_f32_16x16x32_bf16(a, b, c, 0, 0, 0);
}

// async global->LDS, 16B per lane; lds base must be wave-uniform.
__device__ __forceinline__ void gload_lds16(const void* g, void* l) {
  __builtin_amdgcn_global_load_lds(
      (const __attribute__((address_space(1))) unsigned int*)g,
      (__attribute__((address_space(3))) unsigned int*)l, 16, 0, 0);
}

// ---------------------------------------------------------------------------
// K0: weight prep. opw=bf16(pw); ow1=bf16(f1*lnw) (LN-gamma folded);
// of2=bf16(f2); of1bp = f1b + f1 @ lnb (LN-beta folded).
// ---------------------------------------------------------------------------
__global__ void cvt_kernel(const float* __restrict__ pw, const float* __restrict__ f1,
                           const float* __restrict__ f2, const float* __restrict__ lnw,
                           const float* __restrict__ lnb, const float* __restrict__ f1b,
                           unsigned short* __restrict__ opw, unsigned short* __restrict__ ow1,
                           unsigned short* __restrict__ of2, float* __restrict__ of1bp) {
  const long stride = (long)gridDim.x * blockDim.x;
  const long t0 = (long)blockIdx.x * blockDim.x + threadIdx.x;
  for (long i = t0; i < 512L * 512; i += stride) opw[i] = f2bf(pw[i]);
  for (long i = t0; i < 2048L * 512; i += stride)
    ow1[i] = f2bf(f1[i] * lnw[i & 511]);
  for (long i = t0; i < 512L * 2048; i += stride) of2[i] = f2bf(f2[i]);
  for (long i = t0; i < 2048; i += stride) {
    float s = f1b[i];
    const float* fr = f1 + i * 512;
    for (int c = 0; c < 512; ++c) s += fr[c] * lnb[c];
    of1bp[i] = s;
  }
}

// ---------------------------------------------------------------------------
// K1: window attention. grid=1024 windows, 256 thr (4 waves), 4 heads/wave.
// ---------------------------------------------------------------------------
__global__ __launch_bounds__(256) void attn_kernel(
    const float* __restrict__ q, const float* __restrict__ k,
    const float* __restrict__ v, const float* __restrict__ rpb,
    unsigned short* __restrict__ O) {
  __shared__ __align__(16) unsigned short Plds[4][64][72];  // bf16 P, +8 pad
  const int w = blockIdx.x;
  const int tid = threadIdx.x;
  const int wv = tid >> 6;
  const int lane = tid & 63;
  const int l16 = lane & 15;
  const int g = lane >> 4;
  unsigned short (*P)[72] = Plds[wv];
  const float scale = 0.17677669529663687f;  // 32^-0.5
  const long base = (long)w * (64 * 512);

  for (int hi = 0; hi < 4; ++hi) {
    const int h = wv * 4 + hi;
    bf16x8 aq[4], bk[4];
#pragma unroll
    for (int t = 0; t < 4; ++t) {
      const float* qp = q + base + (long)(t * 16 + l16) * 512 + h * 32 + g * 8;
      const float* kp = k + base + (long)(t * 16 + l16) * 512 + h * 32 + g * 8;
      f32x4 q0 = *(const f32x4*)qp, q1 = *(const f32x4*)(qp + 4);
      f32x4 k0 = *(const f32x4*)kp, k1 = *(const f32x4*)(kp + 4);
#pragma unroll
      for (int j = 0; j < 4; ++j) {
        aq[t][j]     = (short)f2bf(q0[j] * scale);
        aq[t][j + 4] = (short)f2bf(q1[j] * scale);
        bk[t][j]     = (short)f2bf(k0[j]);
        bk[t][j + 4] = (short)f2bf(k1[j]);
      }
    }
    f32x4 acc[4][4];
#pragma unroll
    for (int a = 0; a < 4; ++a)
#pragma unroll
      for (int b = 0; b < 4; ++b) acc[a][b] = zero4();
#pragma unroll
    for (int a = 0; a < 4; ++a)
#pragma unroll
      for (int b = 0; b < 4; ++b) acc[a][b] = mfma16(aq[a], bk[b], acc[a][b]);

#pragma unroll
    for (int tm = 0; tm < 4; ++tm) {
      f32x4 mx;
#pragma unroll
      for (int i = 0; i < 4; ++i)
        mx[i] = fmaxf(fmaxf(acc[tm][0][i], acc[tm][1][i]),
                      fmaxf(acc[tm][2][i], acc[tm][3][i]));
#pragma unroll
      for (int off = 1; off < 16; off <<= 1)
#pragma unroll
        for (int i = 0; i < 4; ++i)
          mx[i] = fmaxf(mx[i], __shfl_xor(mx[i], off, 64));
      f32x4 sm = zero4();
#pragma unroll
      for (int tc = 0; tc < 4; ++tc)
#pragma unroll
        for (int i = 0; i < 4; ++i) {
          acc[tm][tc][i] = __expf(acc[tm][tc][i] - mx[i]);
          sm[i] += acc[tm][tc][i];
        }
#pragma unroll
      for (int off = 1; off < 16; off <<= 1)
#pragma unroll
        for (int i = 0; i < 4; ++i) sm[i] += __shfl_xor(sm[i], off, 64);
      f32x4 inv;
#pragma unroll
      for (int i = 0; i < 4; ++i) inv[i] = 1.0f / sm[i];
#pragma unroll
      for (int tc = 0; tc < 4; ++tc)
#pragma unroll
        for (int i = 0; i < 4; ++i) {
          int n = tm * 16 + g * 4 + i;   // query token (row)
          int m = tc * 16 + l16;         // key token (col)
          int idx = ((n >> 3) - (m >> 3) + 7) * 15 + ((n & 7) - (m & 7) + 7);
          P[n][m] = f2bf(acc[tm][tc][i] * inv[i] + rpb[idx * 16 + h]);
        }
    }

    f32x4 oc[4][2];
#pragma unroll
    for (int a = 0; a < 4; ++a) { oc[a][0] = zero4(); oc[a][1] = zero4(); }
#pragma unroll
    for (int ks = 0; ks < 2; ++ks) {
      bf16x8 ap[4];
#pragma unroll
      for (int tm = 0; tm < 4; ++tm)
        ap[tm] = *(const bf16x8*)&P[tm * 16 + l16][ks * 32 + g * 8];
      bf16x8 bv[2];
#pragma unroll
      for (int tn = 0; tn < 2; ++tn)
#pragma unroll
        for (int j = 0; j < 8; ++j) {
          int m = ks * 32 + g * 8 + j;
          bv[tn][j] = (short)f2bf(v[base + (long)m * 512 + h * 32 + tn * 16 + l16]);
        }
#pragma unroll
      for (int tm = 0; tm < 4; ++tm)
#pragma unroll
        for (int tn = 0; tn < 2; ++tn) oc[tm][tn] = mfma16(ap[tm], bv[tn], oc[tm][tn]);
    }
#pragma unroll
    for (int tm = 0; tm < 4; ++tm)
#pragma unroll
      for (int tn = 0; tn < 2; ++tn)
#pragma unroll
        for (int i = 0; i < 4; ++i) {
          int n = tm * 16 + g * 4 + i;
          O[base + (long)n * 512 + h * 32 + tn * 16 + l16] = f2bf(oc[tm][tn][i]);
        }
  }
}

// ---------------------------------------------------------------------------
// K2: proj GEMM (per window 64x512x512) + bias + gamma1*() + x residual,
// scattered (window_reverse) into y == d_out (f32).
// ---------------------------------------------------------------------------
__global__ __launch_bounds__(256) void proj_kernel(
    const unsigned short* __restrict__ O, const unsigned short* __restrict__ pw,
    const float* __restrict__ pb, const float* __restrict__ gamma1,
    const float* __restrict__ x, float* __restrict__ y) {
  const int w = blockIdx.x;
  const int tid = threadIdx.x;
  const int wv = tid >> 6, lane = tid & 63;
  const int l16 = lane & 15, g = lane >> 4;
  const long obase = (long)w * (64 * 512);
  f32x4 acc[4][8];
#pragma unroll
  for (int a = 0; a < 4; ++a)
#pragma unroll
    for (int b = 0; b < 8; ++b) acc[a][b] = zero4();

  for (int kk = 0; kk < 512; kk += 32) {
    bf16x8 a[4];
#pragma unroll
    for (int tm = 0; tm < 4; ++tm)
      a[tm] = *(const bf16x8*)(O + obase + (long)(tm * 16 + l16) * 512 + kk + g * 8);
#pragma unroll
    for (int tn = 0; tn < 8; ++tn) {
      int c = wv * 128 + tn * 16 + l16;
      bf16x8 b = *(const bf16x8*)(pw + (long)c * 512 + kk + g * 8);
#pragma unroll
      for (int tm = 0; tm < 4; ++tm) acc[tm][tn] = mfma16(a[tm], b, acc[tm][tn]);
    }
  }
  const int bi = w >> 6, wh = (w >> 3) & 7, wc = w & 7;
#pragma unroll
  for (int tn = 0; tn < 8; ++tn) {
    int c = wv * 128 + tn * 16 + l16;
    float g1c = gamma1[c], pbc = pb[c];
#pragma unroll
    for (int tm = 0; tm < 4; ++tm)
#pragma unroll
      for (int i = 0; i < 4; ++i) {
        int n = tm * 16 + g * 4 + i;
        long t = (long)(bi * 64 + wh * 8 + (n >> 3)) * 64 + wc * 8 + (n & 7);
        y[t * 512 + c] = x[t * 512 + c] + g1c * (acc[tm][tn][i] + pbc);
      }
  }
}

// ---------------------------------------------------------------------------
// K3a: LN row stats (mu, rsqrt(var+eps)) for all 65536 tokens -> murs.
// ---------------------------------------------------------------------------
__global__ __launch_bounds__(256) void ln_stats_kernel(const float* __restrict__ y,
                                                       float* __restrict__ murs) {
  const int tid = threadIdx.x;
  const long row = (long)blockIdx.x * 64 + (tid >> 2);
  const int sg = tid & 3;
  const float* yr = y + row * 512 + sg * 128;
  float s = 0.f, s2 = 0.f;
  for (int j = 0; j < 128; j += 4) {
    f32x4 t = *(const f32x4*)(yr + j);
    s += t[0] + t[1] + t[2] + t[3];
    s2 += t[0] * t[0] + t[1] * t[1] + t[2] * t[2] + t[3] * t[3];
  }
  s += __shfl_xor(s, 1, 64);  s += __shfl_xor(s, 2, 64);
  s2 += __shfl_xor(s2, 1, 64); s2 += __shfl_xor(s2, 2, 64);
  if (sg == 0) {
    float mu = s * (1.f / 512.f);
    murs[row * 2] = mu;
    murs[row * 2 + 1] = rsqrtf(s2 * (1.f / 512.f) - mu * mu + 1e-5f);
  }
}

// ---------------------------------------------------------------------------
// K3b: fc1 GEMM  h1 = gelu( xn @ w1s^T + f1bp ),  xn = (y-mu)*rs on the fly.
// Tile 128x128, K=512. A staged via normalize+ds_write, B via global_load_lds.
// grid = 2048 (16 col-tiles inner, 128 row-tiles outer). 3 blocks/CU target.
// ---------------------------------------------------------------------------
__global__ __launch_bounds__(256, 3) void fc1_kernel(
    const float* __restrict__ y, const float* __restrict__ murs,
    const unsigned short* __restrict__ w1s, const float* __restrict__ f1bp,
    unsigned short* __restrict__ h1, int tok0) {
  __shared__ __align__(16) unsigned char smem[17408];
  unsigned short* As = (unsigned short*)smem;            // [128][32]
  unsigned short* Bs = (unsigned short*)(smem + 8192);   // [128][32]
  unsigned short* ep = (unsigned short*)smem;            // [128][68] (epilogue)
  const int bid = blockIdx.x;
  const int ct = bid & 15, rt = bid >> 4;
  const int c0 = ct * 128;
  const int tid = threadIdx.x;
  const int wv = tid >> 6, lane = tid & 63;
  const int l16 = lane & 15, g = lane >> 4;
  const int wr = wv >> 1, wc = wv & 1;
  const long t0 = (long)tok0 + (long)rt * 128;

  const int sr = tid >> 1, sh = tid & 1;   // staging: row, half
  const float mu = murs[(t0 + sr) * 2];
  const float rs = murs[(t0 + sr) * 2 + 1];
  const float* xr = y + (t0 + sr) * 512 + sh * 16;

  f32x4 acc[4][4];
#pragma unroll
  for (int a = 0; a < 4; ++a)
#pragma unroll
    for (int b = 0; b < 4; ++b) acc[a][b] = zero4();

  for (int kk = 0; kk < 512; kk += 32) {
    // A: normalize 16 floats -> bf16 LDS [sr][sh*16..+16)
    f32x4 xv[4];
#pragma unroll
    for (int j = 0; j < 4; ++j) xv[j] = *(const f32x4*)(xr + kk + j * 4);
    u16x8 p0, p1;
#pragma unroll
    for (int e = 0; e < 4; ++e) {
      p0[e]     = f2bf((xv[0][e] - mu) * rs);
      p0[e + 4] = f2bf((xv[1][e] - mu) * rs);
      p1[e]     = f2bf((xv[2][e] - mu) * rs);
      p1[e + 4] = f2bf((xv[3][e] - mu) * rs);
    }
    *(u16x8*)(As + sr * 32 + sh * 16) = p0;
    *(u16x8*)(As + sr * 32 + sh * 16 + 8) = p1;
    // B: w1s rows c0..c0+127, cols kk..kk+31 -> [128][32]; 2 issues/wave
#pragma unroll
    for (int iss = 0; iss < 2; ++iss) {
      int r = wv * 32 + iss * 16 + (lane >> 2);
      gload_lds16(w1s + (long)(c0 + r) * 512 + kk + (lane & 3) * 8,
                  Bs + (wv * 32 + iss * 16) * 32);
    }
    __syncthreads();
    bf16x8 a[4], b[4];
#pragma unroll
    for (int tm = 0; tm < 4; ++tm)
      a[tm] = *(const bf16x8*)(As + (wr * 64 + tm * 16 + l16) * 32 + g * 8);
#pragma unroll
    for (int tn = 0; tn < 4; ++tn)
      b[tn] = *(const bf16x8*)(Bs + (wc * 64 + tn * 16 + l16) * 32 + g * 8);
#pragma unroll
    for (int tm = 0; tm < 4; ++tm)
#pragma unroll
      for (int tn = 0; tn < 4; ++tn) acc[tm][tn] = mfma16(a[tm], b[tn], acc[tm][tn]);
    __syncthreads();
  }

  // epilogue: GELU -> LDS bounce -> coalesced bf16 stores (2 chunks of 64 cols)
#pragma unroll
  for (int cc = 0; cc < 2; ++cc) {
    if (wc == cc) {
#pragma unroll
      for (int tm = 0; tm < 4; ++tm)
#pragma unroll
        for (int tn = 0; tn < 4; ++tn)
#pragma unroll
          for (int i = 0; i < 4; ++i) {
            int row = wr * 64 + tm * 16 + g * 4 + i;
            int col = tn * 16 + l16;
            float v = acc[tm][tn][i] + f1bp[c0 + cc * 64 + col];
            float ge = 0.5f * v * (1.f + erff(v * 0.70710678118654752f));
            ep[row * 68 + col] = f2bf(ge);
          }
    }
    __syncthreads();
    const int row = tid >> 1, hf = tid & 1;
    unsigned short* dst = h1 + ((long)rt * 128 + row) * 2048 + c0 + cc * 64 + hf * 32;
#pragma unroll
    for (int j = 0; j < 4; ++j)
      *(u16x8*)(dst + j * 8) = *(const u16x8*)(ep + row * 68 + hf * 32 + j * 8);
    __syncthreads();
  }
}

// ---------------------------------------------------------------------------
// K3c: fc2 GEMM  y += g2 * ( h1 @ f2^T + f2b ).  Tile 128x128, K=2048.
// A (h1) and B (w2) both via global_load_lds. grid = 512.
// ---------------------------------------------------------------------------
__global__ __launch_bounds__(256, 3) void fc2_kernel(
    const unsigned short* __restrict__ h1, const unsigned short* __restrict__ w2,
    const float* __restrict__ f2b, const float* __restrict__ g2,
    float* __restrict__ y, int tok0) {
  __shared__ __align__(16) unsigned short As[128 * 32];
  __shared__ __align__(16) unsigned short Bs[128 * 32];
  const int bid = blockIdx.x;
  const int ct = bid & 3, rt = bid >> 2;
  const int c0 = ct * 128;
  const int tid = threadIdx.x;
  const int wv = tid >> 6, lane = tid & 63;
  const int l16 = lane & 15, g = lane >> 4;
  const int wr = wv >> 1, wc = wv & 1;

  f32x4 acc[4][4];
#pragma unroll
  for (int a = 0; a < 4; ++a)
#pragma unroll
    for (int b = 0; b < 4; ++b) acc[a][b] = zero4();

  for (int kk = 0; kk < 2048; kk += 32) {
#pragma unroll
    for (int iss = 0; iss < 2; ++iss) {
      int r = wv * 32 + iss * 16 + (lane >> 2);
      int cb = (lane & 3) * 8;
      gload_lds16(h1 + ((long)rt * 128 + r) * 2048 + kk + cb,
                  As + (wv * 32 + iss * 16) * 32);
      gload_lds16(w2 + (long)(c0 + r) * 2048 + kk + cb,
                  Bs + (wv * 32 + iss * 16) * 32);
    }
    __syncthreads();
    bf16x8 a[4], b[4];
#pragma unroll
    for (int tm = 0; tm < 4; ++tm)
      a[tm] = *(const bf16x8*)(As + (wr * 64 + tm * 16 + l16) * 32 + g * 8);
#pragma unroll
    for (int tn = 0; tn < 4; ++tn)
      b[tn] = *(const bf16x8*)(Bs + (wc * 64 + tn * 16 + l16) * 32 + g * 8);
#pragma unroll
    for (int tm = 0; tm < 4; ++tm)
#pragma unroll
      for (int tn = 0; tn < 4; ++tn) acc[tm][tn] = mfma16(a[tm], b[tn], acc[tm][tn]);
    __syncthreads();
  }

#pragma unroll
  for (int tn = 0; tn < 4; ++tn) {
    int c = c0 + wc * 64 + tn * 16 + l16;
    float gc = g2[c], bc = f2b[c];
#pragma unroll
    for (int tm = 0; tm < 4; ++tm)
#pragma unroll
      for (int i = 0; i < 4; ++i) {
        long t = (long)tok0 + (long)rt * 128 + wr * 64 + tm * 16 + g * 4 + i;
        y[t * 512 + c] += gc * (acc[tm][tn][i] + bc);
      }
  }
}

// ---------------------------------------------------------------------------
extern "C" void kernel_launch(void* const* d_in, const int* in_sizes, int n_in,
                              void* d_out, int out_size, void* d_ws, size_t ws_size,
                              hipStream_t stream) {
  const float* x   = (const float*)d_in[0];
  const float* q   = (const float*)d_in[1];
  const float* k   = (const float*)d_in[2];
  const float* v   = (const float*)d_in[3];
  const float* pw  = (const float*)d_in[4];
  const float* pb  = (const float*)d_in[5];
  const float* rpb = (const float*)d_in[6];
  const float* g1  = (const float*)d_in[7];
  const float* lnw = (const float*)d_in[8];
  const float* lnb = (const float*)d_in[9];
  const float* f1w = (const float*)d_in[10];
  const float* f1b = (const float*)d_in[11];
  const float* f2w = (const float*)d_in[12];
  const float* f2b = (const float*)d_in[13];
  const float* g2  = (const float*)d_in[14];
  float* y = (float*)d_out;

  // ws layout (ushort elements unless noted):
  unsigned short* Ob   = (unsigned short*)d_ws;            // 33,554,432 els (64MB); reused as h1
  unsigned short* opw  = Ob + (size_t)1024 * 64 * 512;     // 512*512
  unsigned short* ow1  = opw + 512 * 512;                  // 2048*512 (lnw-folded)
  unsigned short* of2  = ow1 + 2048 * 512;                 // 512*2048
  float* of1bp = (float*)(of2 + 512 * 2048);               // 2048 f32 (lnb-folded bias)
  float* murs  = of1bp + 2048;                             // 65536*2 f32
  unsigned short* h1 = Ob;                                 // 16384*2048 per pass

  hipLaunchKernelGGL(cvt_kernel, dim3(1024), dim3(256), 0, stream,
                     pw, f1w, f2w, lnw, lnb, f1b, opw, ow1, of2, of1bp);
  hipLaunchKernelGGL(attn_kernel, dim3(1024), dim3(256), 0, stream,
                     q, k, v, rpb, Ob);
  hipLaunchKernelGGL(proj_kernel, dim3(1024), dim3(256), 0, stream,
                     Ob, opw, pb, g1, x, y);
  hipLaunchKernelGGL(ln_stats_kernel, dim3(1024), dim3(256), 0, stream, y, murs);
  for (int p = 0; p < 4; ++p) {
    hipLaunchKernelGGL(fc1_kernel, dim3(2048), dim3(256), 0, stream,
                       y, murs, ow1, of1bp, h1, p * 16384);
    hipLaunchKernelGGL(fc2_kernel, dim3(512), dim3(256), 0, stream,
                       h1, of2, f2b, g2, y, p * 16384);
  }
}

// Round 13
// 1304.601 us; speedup vs baseline: 1.5276x; 1.1051x over previous
//
#include <hip/hip_runtime.h>
#include <math.h>

typedef __attribute__((ext_vector_type(4))) float f32x4;
typedef __attribute__((ext_vector_type(8))) short bf16x8;
typedef __attribute__((ext_vector_type(4))) unsigned short u16x4;
typedef __attribute__((ext_vector_type(8))) unsigned short u16x8;

__device__ __forceinline__ unsigned short f2bf(float f) {
  union { float f; unsigned u; } v; v.f = f;
  return (unsigned short)((v.u + 0x7fffu + ((v.u >> 16) & 1u)) >> 16);
}

__device__ __forceinline__ f32x4 zero4() {
  f32x4 z; z[0] = z[1] = z[2] = z[3] = 0.f; return z;
}

__device__ __forceinline__ f32x4 mfma16(bf16x8 a, bf16x8 b, f32x4 c) {
  return __builtin_amdgcn_mfma_f32_16x16x32_bf16(a, b, c, 0, 0, 0);
}

// async global->LDS, 16B per lane; lds base must be wave-uniform.
__device__ __forceinline__ void gload_lds16(const void* g, void* l) {
  __builtin_amdgcn_global_load_lds(
      (const __attribute__((address_space(1))) unsigned int*)g,
      (__attribute__((address_space(3))) unsigned int*)l, 16, 0, 0);
}

// ---------------------------------------------------------------------------
// K0: weight prep. opw=bf16(pw); ow1=bf16(f1*lnw) (LN-gamma folded);
// of2=bf16(f2); of1bp = f1b + f1 @ lnb (LN-beta folded).
// ---------------------------------------------------------------------------
__global__ void cvt_kernel(const float* __restrict__ pw, const float* __restrict__ f1,
                           const float* __restrict__ f2, const float* __restrict__ lnw,
                           const float* __restrict__ lnb, const float* __restrict__ f1b,
                           unsigned short* __restrict__ opw, unsigned short* __restrict__ ow1,
                           unsigned short* __restrict__ of2, float* __restrict__ of1bp) {
  const long stride = (long)gridDim.x * blockDim.x;
  const long t0 = (long)blockIdx.x * blockDim.x + threadIdx.x;
  for (long i = t0; i < 512L * 512; i += stride) opw[i] = f2bf(pw[i]);
  for (long i = t0; i < 2048L * 512; i += stride)
    ow1[i] = f2bf(f1[i] * lnw[i & 511]);
  for (long i = t0; i < 512L * 2048; i += stride) of2[i] = f2bf(f2[i]);
  for (long i = t0; i < 2048; i += stride) {
    float s = f1b[i];
    const float* fr = f1 + i * 512;
    for (int c = 0; c < 512; ++c) s += fr[c] * lnb[c];
    of1bp[i] = s;
  }
}

// ---------------------------------------------------------------------------
// K1 v2: window attention. grid = 4096 = 1024 windows x 4 head-quads.
// 4 waves/block, each wave computes ONE head (h = hq*4 + wv). rpb staged in
// LDS per block. 4x more blocks than v1 -> ~3 co-resident blocks/CU hides
// the serial QK->softmax->PV chain that left v1 at 1% MFMA / 12% occupancy.
// ---------------------------------------------------------------------------
__global__ __launch_bounds__(256, 3) void attn_kernel(
    const float* __restrict__ q, const float* __restrict__ k,
    const float* __restrict__ v, const float* __restrict__ rpb,
    unsigned short* __restrict__ O) {
  __shared__ __align__(16) unsigned short Plds[4][64][72];  // bf16 P per wave
  __shared__ float rpb_s[225 * 4];                          // bias cols for this head-quad
  const int w = blockIdx.x >> 2;
  const int hq = blockIdx.x & 3;
  const int tid = threadIdx.x;
  const int wv = tid >> 6;
  const int lane = tid & 63;
  const int l16 = lane & 15;
  const int g = lane >> 4;
  unsigned short (*P)[72] = Plds[wv];
  const float scale = 0.17677669529663687f;  // 32^-0.5
  const long base = (long)w * (64 * 512);
  const int h = hq * 4 + wv;

  // stage rel-pos bias columns hq*4..hq*4+3 -> LDS [idx][c]
  for (int i = tid; i < 225 * 4; i += 256)
    rpb_s[i] = rpb[(i >> 2) * 16 + hq * 4 + (i & 3)];
  __syncthreads();

  bf16x8 aq[4], bk[4];
#pragma unroll
  for (int t = 0; t < 4; ++t) {
    const float* qp = q + base + (long)(t * 16 + l16) * 512 + h * 32 + g * 8;
    const float* kp = k + base + (long)(t * 16 + l16) * 512 + h * 32 + g * 8;
    f32x4 q0 = *(const f32x4*)qp, q1 = *(const f32x4*)(qp + 4);
    f32x4 k0 = *(const f32x4*)kp, k1 = *(const f32x4*)(kp + 4);
#pragma unroll
    for (int j = 0; j < 4; ++j) {
      aq[t][j]     = (short)f2bf(q0[j] * scale);
      aq[t][j + 4] = (short)f2bf(q1[j] * scale);
      bk[t][j]     = (short)f2bf(k0[j]);
      bk[t][j + 4] = (short)f2bf(k1[j]);
    }
  }
  f32x4 acc[4][4];
#pragma unroll
  for (int a = 0; a < 4; ++a)
#pragma unroll
    for (int b = 0; b < 4; ++b) acc[a][b] = zero4();
#pragma unroll
  for (int a = 0; a < 4; ++a)
#pragma unroll
    for (int b = 0; b < 4; ++b) acc[a][b] = mfma16(aq[a], bk[b], acc[a][b]);

  // softmax over 64 cols per row, then + bias (AFTER softmax) -> LDS bf16
#pragma unroll
  for (int tm = 0; tm < 4; ++tm) {
    f32x4 mx;
#pragma unroll
    for (int i = 0; i < 4; ++i)
      mx[i] = fmaxf(fmaxf(acc[tm][0][i], acc[tm][1][i]),
                    fmaxf(acc[tm][2][i], acc[tm][3][i]));
#pragma unroll
    for (int off = 1; off < 16; off <<= 1)
#pragma unroll
      for (int i = 0; i < 4; ++i)
        mx[i] = fmaxf(mx[i], __shfl_xor(mx[i], off, 64));
    f32x4 sm = zero4();
#pragma unroll
    for (int tc = 0; tc < 4; ++tc)
#pragma unroll
      for (int i = 0; i < 4; ++i) {
        acc[tm][tc][i] = __expf(acc[tm][tc][i] - mx[i]);
        sm[i] += acc[tm][tc][i];
      }
#pragma unroll
    for (int off = 1; off < 16; off <<= 1)
#pragma unroll
      for (int i = 0; i < 4; ++i) sm[i] += __shfl_xor(sm[i], off, 64);
    f32x4 inv;
#pragma unroll
    for (int i = 0; i < 4; ++i) inv[i] = 1.0f / sm[i];
#pragma unroll
    for (int tc = 0; tc < 4; ++tc)
#pragma unroll
      for (int i = 0; i < 4; ++i) {
        int n = tm * 16 + g * 4 + i;   // query token (row)
        int m = tc * 16 + l16;         // key token (col)
        int idx = ((n >> 3) - (m >> 3) + 7) * 15 + ((n & 7) - (m & 7) + 7);
        P[n][m] = f2bf(acc[tm][tc][i] * inv[i] + rpb_s[idx * 4 + wv]);
      }
  }

  // O = P @ vh   (M=64 x N=32 x K=64 -> 4x2 tiles, 2 k-steps)
  f32x4 oc[4][2];
#pragma unroll
  for (int a = 0; a < 4; ++a) { oc[a][0] = zero4(); oc[a][1] = zero4(); }
#pragma unroll
  for (int ks = 0; ks < 2; ++ks) {
    bf16x8 ap[4];
#pragma unroll
    for (int tm = 0; tm < 4; ++tm)
      ap[tm] = *(const bf16x8*)&P[tm * 16 + l16][ks * 32 + g * 8];
    bf16x8 bv[2];
#pragma unroll
    for (int tn = 0; tn < 2; ++tn)
#pragma unroll
      for (int j = 0; j < 8; ++j) {
        int m = ks * 32 + g * 8 + j;
        bv[tn][j] = (short)f2bf(v[base + (long)m * 512 + h * 32 + tn * 16 + l16]);
      }
#pragma unroll
    for (int tm = 0; tm < 4; ++tm)
#pragma unroll
      for (int tn = 0; tn < 2; ++tn) oc[tm][tn] = mfma16(ap[tm], bv[tn], oc[tm][tn]);
  }
#pragma unroll
  for (int tm = 0; tm < 4; ++tm)
#pragma unroll
    for (int tn = 0; tn < 2; ++tn)
#pragma unroll
      for (int i = 0; i < 4; ++i) {
        int n = tm * 16 + g * 4 + i;
        O[base + (long)n * 512 + h * 32 + tn * 16 + l16] = f2bf(oc[tm][tn][i]);
      }
}

// ---------------------------------------------------------------------------
// K2 v2: proj GEMM, fc2-style tiling. Tile 128 tokens x 128 chans, K=512.
// A = O (2 consecutive windows = 128 contiguous rows), B = pw, both via
// global_load_lds. Epilogue: window-reverse scatter + x + gamma1*(.+pb).
// grid = 512 row-tiles x 4 col-tiles = 2048.
// ---------------------------------------------------------------------------
__global__ __launch_bounds__(256, 3) void proj_kernel(
    const unsigned short* __restrict__ O, const unsigned short* __restrict__ pw,
    const float* __restrict__ pb, const float* __restrict__ gamma1,
    const float* __restrict__ x, float* __restrict__ y) {
  __shared__ __align__(16) unsigned short As[128 * 32];
  __shared__ __align__(16) unsigned short Bs[128 * 32];
  const int bid = blockIdx.x;
  const int ct = bid & 3, rt = bid >> 2;
  const int c0 = ct * 128;
  const int tid = threadIdx.x;
  const int wv = tid >> 6, lane = tid & 63;
  const int l16 = lane & 15, g = lane >> 4;
  const int wr = wv >> 1, wc = wv & 1;

  f32x4 acc[4][4];
#pragma unroll
  for (int a = 0; a < 4; ++a)
#pragma unroll
    for (int b = 0; b < 4; ++b) acc[a][b] = zero4();

  for (int kk = 0; kk < 512; kk += 32) {
#pragma unroll
    for (int iss = 0; iss < 2; ++iss) {
      int r = wv * 32 + iss * 16 + (lane >> 2);
      int cb = (lane & 3) * 8;
      gload_lds16(O + ((long)rt * 128 + r) * 512 + kk + cb,
                  As + (wv * 32 + iss * 16) * 32);
      gload_lds16(pw + (long)(c0 + r) * 512 + kk + cb,
                  Bs + (wv * 32 + iss * 16) * 32);
    }
    __syncthreads();
    bf16x8 a[4], b[4];
#pragma unroll
    for (int tm = 0; tm < 4; ++tm)
      a[tm] = *(const bf16x8*)(As + (wr * 64 + tm * 16 + l16) * 32 + g * 8);
#pragma unroll
    for (int tn = 0; tn < 4; ++tn)
      b[tn] = *(const bf16x8*)(Bs + (wc * 64 + tn * 16 + l16) * 32 + g * 8);
#pragma unroll
    for (int tm = 0; tm < 4; ++tm)
#pragma unroll
      for (int tn = 0; tn < 4; ++tn) acc[tm][tn] = mfma16(a[tm], b[tn], acc[tm][tn]);
    __syncthreads();
  }

#pragma unroll
  for (int tn = 0; tn < 4; ++tn) {
    int c = c0 + wc * 64 + tn * 16 + l16;
    float g1c = gamma1[c], pbc = pb[c];
#pragma unroll
    for (int tm = 0; tm < 4; ++tm)
#pragma unroll
      for (int i = 0; i < 4; ++i) {
        int t2 = rt * 128 + wr * 64 + tm * 16 + g * 4 + i;  // O-order token
        int ww = t2 >> 6, n = t2 & 63;
        int bi = ww >> 6, wh = (ww >> 3) & 7, wcol = ww & 7;
        long t = (long)(bi * 64 + wh * 8 + (n >> 3)) * 64 + wcol * 8 + (n & 7);
        y[t * 512 + c] = x[t * 512 + c] + g1c * (acc[tm][tn][i] + pbc);
      }
  }
}

// ---------------------------------------------------------------------------
// K3a: LN row stats (mu, rsqrt(var+eps)) for all 65536 tokens -> murs.
// ---------------------------------------------------------------------------
__global__ __launch_bounds__(256) void ln_stats_kernel(const float* __restrict__ y,
                                                       float* __restrict__ murs) {
  const int tid = threadIdx.x;
  const long row = (long)blockIdx.x * 64 + (tid >> 2);
  const int sg = tid & 3;
  const float* yr = y + row * 512 + sg * 128;
  float s = 0.f, s2 = 0.f;
  for (int j = 0; j < 128; j += 4) {
    f32x4 t = *(const f32x4*)(yr + j);
    s += t[0] + t[1] + t[2] + t[3];
    s2 += t[0] * t[0] + t[1] * t[1] + t[2] * t[2] + t[3] * t[3];
  }
  s += __shfl_xor(s, 1, 64);  s += __shfl_xor(s, 2, 64);
  s2 += __shfl_xor(s2, 1, 64); s2 += __shfl_xor(s2, 2, 64);
  if (sg == 0) {
    float mu = s * (1.f / 512.f);
    murs[row * 2] = mu;
    murs[row * 2 + 1] = rsqrtf(s2 * (1.f / 512.f) - mu * mu + 1e-5f);
  }
}

// ---------------------------------------------------------------------------
// K3b: fc1 GEMM  h1 = gelu( xn @ w1s^T + f1bp ),  xn = (y-mu)*rs on the fly.
// ---------------------------------------------------------------------------
__global__ __launch_bounds__(256, 3) void fc1_kernel(
    const float* __restrict__ y, const float* __restrict__ murs,
    const unsigned short* __restrict__ w1s, const float* __restrict__ f1bp,
    unsigned short* __restrict__ h1, int tok0) {
  __shared__ __align__(16) unsigned char smem[17408];
  unsigned short* As = (unsigned short*)smem;            // [128][32]
  unsigned short* Bs = (unsigned short*)(smem + 8192);   // [128][32]
  unsigned short* ep = (unsigned short*)smem;            // [128][68] (epilogue)
  const int bid = blockIdx.x;
  const int ct = bid & 15, rt = bid >> 4;
  const int c0 = ct * 128;
  const int tid = threadIdx.x;
  const int wv = tid >> 6, lane = tid & 63;
  const int l16 = lane & 15, g = lane >> 4;
  const int wr = wv >> 1, wc = wv & 1;
  const long t0 = (long)tok0 + (long)rt * 128;

  const int sr = tid >> 1, sh = tid & 1;   // staging: row, half
  const float mu = murs[(t0 + sr) * 2];
  const float rs = murs[(t0 + sr) * 2 + 1];
  const float* xr = y + (t0 + sr) * 512 + sh * 16;

  f32x4 acc[4][4];
#pragma unroll
  for (int a = 0; a < 4; ++a)
#pragma unroll
    for (int b = 0; b < 4; ++b) acc[a][b] = zero4();

  for (int kk = 0; kk < 512; kk += 32) {
    f32x4 xv[4];
#pragma unroll
    for (int j = 0; j < 4; ++j) xv[j] = *(const f32x4*)(xr + kk + j * 4);
    u16x8 p0, p1;
#pragma unroll
    for (int e = 0; e < 4; ++e) {
      p0[e]     = f2bf((xv[0][e] - mu) * rs);
      p0[e + 4] = f2bf((xv[1][e] - mu) * rs);
      p1[e]     = f2bf((xv[2][e] - mu) * rs);
      p1[e + 4] = f2bf((xv[3][e] - mu) * rs);
    }
    *(u16x8*)(As + sr * 32 + sh * 16) = p0;
    *(u16x8*)(As + sr * 32 + sh * 16 + 8) = p1;
#pragma unroll
    for (int iss = 0; iss < 2; ++iss) {
      int r = wv * 32 + iss * 16 + (lane >> 2);
      gload_lds16(w1s + (long)(c0 + r) * 512 + kk + (lane & 3) * 8,
                  Bs + (wv * 32 + iss * 16) * 32);
    }
    __syncthreads();
    bf16x8 a[4], b[4];
#pragma unroll
    for (int tm = 0; tm < 4; ++tm)
      a[tm] = *(const bf16x8*)(As + (wr * 64 + tm * 16 + l16) * 32 + g * 8);
#pragma unroll
    for (int tn = 0; tn < 4; ++tn)
      b[tn] = *(const bf16x8*)(Bs + (wc * 64 + tn * 16 + l16) * 32 + g * 8);
#pragma unroll
    for (int tm = 0; tm < 4; ++tm)
#pragma unroll
      for (int tn = 0; tn < 4; ++tn) acc[tm][tn] = mfma16(a[tm], b[tn], acc[tm][tn]);
    __syncthreads();
  }

#pragma unroll
  for (int cc = 0; cc < 2; ++cc) {
    if (wc == cc) {
#pragma unroll
      for (int tm = 0; tm < 4; ++tm)
#pragma unroll
        for (int tn = 0; tn < 4; ++tn)
#pragma unroll
          for (int i = 0; i < 4; ++i) {
            int row = wr * 64 + tm * 16 + g * 4 + i;
            int col = tn * 16 + l16;
            float v = acc[tm][tn][i] + f1bp[c0 + cc * 64 + col];
            float ge = 0.5f * v * (1.f + erff(v * 0.70710678118654752f));
            ep[row * 68 + col] = f2bf(ge);
          }
    }
    __syncthreads();
    const int row = tid >> 1, hf = tid & 1;
    unsigned short* dst = h1 + ((long)rt * 128 + row) * 2048 + c0 + cc * 64 + hf * 32;
#pragma unroll
    for (int j = 0; j < 4; ++j)
      *(u16x8*)(dst + j * 8) = *(const u16x8*)(ep + row * 68 + hf * 32 + j * 8);
    __syncthreads();
  }
}

// ---------------------------------------------------------------------------
// K3c: fc2 GEMM  y += g2 * ( h1 @ f2^T + f2b ).  Tile 128x128, K=2048.
// ---------------------------------------------------------------------------
__global__ __launch_bounds__(256, 3) void fc2_kernel(
    const unsigned short* __restrict__ h1, const unsigned short* __restrict__ w2,
    const float* __restrict__ f2b, const float* __restrict__ g2,
    float* __restrict__ y, int tok0) {
  __shared__ __align__(16) unsigned short As[128 * 32];
  __shared__ __align__(16) unsigned short Bs[128 * 32];
  const int bid = blockIdx.x;
  const int ct = bid & 3, rt = bid >> 2;
  const int c0 = ct * 128;
  const int tid = threadIdx.x;
  const int wv = tid >> 6, lane = tid & 63;
  const int l16 = lane & 15, g = lane >> 4;
  const int wr = wv >> 1, wc = wv & 1;

  f32x4 acc[4][4];
#pragma unroll
  for (int a = 0; a < 4; ++a)
#pragma unroll
    for (int b = 0; b < 4; ++b) acc[a][b] = zero4();

  for (int kk = 0; kk < 2048; kk += 32) {
#pragma unroll
    for (int iss = 0; iss < 2; ++iss) {
      int r = wv * 32 + iss * 16 + (lane >> 2);
      int cb = (lane & 3) * 8;
      gload_lds16(h1 + ((long)rt * 128 + r) * 2048 + kk + cb,
                  As + (wv * 32 + iss * 16) * 32);
      gload_lds16(w2 + (long)(c0 + r) * 2048 + kk + cb,
                  Bs + (wv * 32 + iss * 16) * 32);
    }
    __syncthreads();
    bf16x8 a[4], b[4];
#pragma unroll
    for (int tm = 0; tm < 4; ++tm)
      a[tm] = *(const bf16x8*)(As + (wr * 64 + tm * 16 + l16) * 32 + g * 8);
#pragma unroll
    for (int tn = 0; tn < 4; ++tn)
      b[tn] = *(const bf16x8*)(Bs + (wc * 64 + tn * 16 + l16) * 32 + g * 8);
#pragma unroll
    for (int tm = 0; tm < 4; ++tm)
#pragma unroll
      for (int tn = 0; tn < 4; ++tn) acc[tm][tn] = mfma16(a[tm], b[tn], acc[tm][tn]);
    __syncthreads();
  }

#pragma unroll
  for (int tn = 0; tn < 4; ++tn) {
    int c = c0 + wc * 64 + tn * 16 + l16;
    float gc = g2[c], bc = f2b[c];
#pragma unroll
    for (int tm = 0; tm < 4; ++tm)
#pragma unroll
      for (int i = 0; i < 4; ++i) {
        long t = (long)tok0 + (long)rt * 128 + wr * 64 + tm * 16 + g * 4 + i;
        y[t * 512 + c] += gc * (acc[tm][tn][i] + bc);
      }
  }
}

// ---------------------------------------------------------------------------
extern "C" void kernel_launch(void* const* d_in, const int* in_sizes, int n_in,
                              void* d_out, int out_size, void* d_ws, size_t ws_size,
                              hipStream_t stream) {
  const float* x   = (const float*)d_in[0];
  const float* q   = (const float*)d_in[1];
  const float* k   = (const float*)d_in[2];
  const float* v   = (const float*)d_in[3];
  const float* pw  = (const float*)d_in[4];
  const float* pb  = (const float*)d_in[5];
  const float* rpb = (const float*)d_in[6];
  const float* g1  = (const float*)d_in[7];
  const float* lnw = (const float*)d_in[8];
  const float* lnb = (const float*)d_in[9];
  const float* f1w = (const float*)d_in[10];
  const float* f1b = (const float*)d_in[11];
  const float* f2w = (const float*)d_in[12];
  const float* f2b = (const float*)d_in[13];
  const float* g2  = (const float*)d_in[14];
  float* y = (float*)d_out;

  // ws layout (ushort elements unless noted):
  unsigned short* Ob   = (unsigned short*)d_ws;            // 64MB; reused as h1
  unsigned short* opw  = Ob + (size_t)1024 * 64 * 512;     // 512*512
  unsigned short* ow1  = opw + 512 * 512;                  // 2048*512 (lnw-folded)
  unsigned short* of2  = ow1 + 2048 * 512;                 // 512*2048
  float* of1bp = (float*)(of2 + 512 * 2048);               // 2048 f32 (lnb-folded bias)
  float* murs  = of1bp + 2048;                             // 65536*2 f32
  unsigned short* h1 = Ob;                                 // 16384*2048 per pass

  hipLaunchKernelGGL(cvt_kernel, dim3(1024), dim3(256), 0, stream,
                     pw, f1w, f2w, lnw, lnb, f1b, opw, ow1, of2, of1bp);
  hipLaunchKernelGGL(attn_kernel, dim3(4096), dim3(256), 0, stream,
                     q, k, v, rpb, Ob);
  hipLaunchKernelGGL(proj_kernel, dim3(2048), dim3(256), 0, stream,
                     Ob, opw, pb, g1, x, y);
  hipLaunchKernelGGL(ln_stats_kernel, dim3(1024), dim3(256), 0, stream, y, murs);
  for (int p = 0; p < 4; ++p) {
    hipLaunchKernelGGL(fc1_kernel, dim3(2048), dim3(256), 0, stream,
                       y, murs, ow1, of1bp, h1, p * 16384);
    hipLaunchKernelGGL(fc2_kernel, dim3(512), dim3(256), 0, stream,
                       h1, of2, f2b, g2, y, p * 16384);
  }
}